// Round 2
// baseline (463.222 us; speedup 1.0000x reference)
//
#include <hip/hip_runtime.h>

namespace {

constexpr int S    = 384;
constexpr int D    = 64;
constexpr int QT   = 16;        // q-rows per tile
constexpr int TPB  = 4;         // tiles per block; 24 tiles/bh -> 6 blocks/bh
constexpr int PROW = 384;       // shorts per P_lds row (48 x 16B k-groups)

typedef float        f32x4  __attribute__((ext_vector_type(4)));
typedef unsigned int u32x2  __attribute__((ext_vector_type(2)));
typedef unsigned int u32x4  __attribute__((ext_vector_type(4)));
typedef __bf16       bf16x8 __attribute__((ext_vector_type(8)));

__device__ __forceinline__ unsigned int f2bf(float f) {
    // round-to-nearest-even fp32 -> bf16 (finite inputs)
    unsigned int u = __float_as_uint(f);
    u += 0x7fffu + ((u >> 16) & 1u);
    return u >> 16;
}

// LDS = P tile only (12.3 KB) -> 3 blocks/CU instead of 2.
// V lives in registers: each wave owns d-columns [wave*16, wave*16+16);
// its 12 MFMA B-fragments (full K=384) are 48 VGPRs, loaded once per block.
__global__ __launch_bounds__(256, 3)
void softmax_drop_pv(const float* __restrict__ scores,
                     const float* __restrict__ vmat,
                     const float* __restrict__ dmask,
                     float* __restrict__ out)
{
    __shared__ alignas(16) unsigned short P_lds[QT * PROW];   // 12 KB
    __shared__ float linv[QT];

    const int tid  = threadIdx.x;
    const int lane = tid & 63;
    const int wave = tid >> 6;    // 0..3
    const int rh   = lane >> 5;   // half-wave id: row of the pair
    const int l32  = lane & 31;
    const int quad = lane >> 4;

    const int bh    = blockIdx.x / 6;                 // 0..383
    const int qbase = (blockIdx.x % 6) * (TPB * QT);  // 0..320 step 64

    unsigned int* P32 = reinterpret_cast<unsigned int*>(P_lds);

    // ---- V -> registers: B-frag layout col=lane&15, k=(s*4+quad)*8+j -----
    // Per-bh V is 96 KB and read by 6 blocks -> L2/L3-served; once per block.
    const int dcol = wave * 16 + (lane & 15);   // wave owns d-quarter
    bf16x8 vfrag[12];
    {
        const float* vb = vmat + (size_t)bh * (S * D) + dcol;
#pragma unroll
        for (int s = 0; s < 12; ++s) {
            const float* vp = vb + (size_t)((s * 4 + quad) * 8) * D;
            u32x4 pk;
            pk.x = f2bf(vp[0 * D]) | (f2bf(vp[1 * D]) << 16);
            pk.y = f2bf(vp[2 * D]) | (f2bf(vp[3 * D]) << 16);
            pk.z = f2bf(vp[4 * D]) | (f2bf(vp[5 * D]) << 16);
            pk.w = f2bf(vp[6 * D]) | (f2bf(vp[7 * D]) << 16);
            vfrag[s] = __builtin_bit_cast(bf16x8, pk);
        }
    }

    // ---- single-buffered register prefetch of scores+mask (nt) ------------
    // Buffer is fully dead by end of phase 0, so re-issuing there gives the
    // same pipeline depth as the old double buffer at half the VGPR cost.
    f32x4 sv[6], mv[6];
    auto prefetch = [&](int t) {
        const int q0 = qbase + t * QT;
        const size_t rb = ((size_t)bh * S + q0) * S;
#pragma unroll
        for (int i = 0; i < 2; ++i) {
            const int row = wave * 4 + 2 * i + rh;
            const f32x4* sp =
                reinterpret_cast<const f32x4*>(scores + rb + (size_t)row * S) + l32;
            const f32x4* mp =
                reinterpret_cast<const f32x4*>(dmask  + rb + (size_t)row * S) + l32;
#pragma unroll
            for (int p = 0; p < 3; ++p) {
                sv[i * 3 + p] = __builtin_nontemporal_load(sp + 32 * p);
                mv[i * 3 + p] = __builtin_nontemporal_load(mp + 32 * p);
            }
        }
    };

    prefetch(0);   // no prologue barrier needed any more (no V staging in LDS)

    const int qrow = lane & 15;           // shared 16-row A tile
    const int qx   = qrow & 7;

#pragma unroll
    for (int t = 0; t < TPB; ++t) {
        const int q0 = qbase + t * QT;

        // ---- phase 0: softmax*mask -> bf16 P (unnormalized), from regs ----
#pragma unroll
        for (int i = 0; i < 2; ++i) {
            const int row = wave * 4 + 2 * i + rh;
            const f32x4 s0 = sv[i*3+0], s1 = sv[i*3+1], s2 = sv[i*3+2];
            const f32x4 m0 = mv[i*3+0], m1 = mv[i*3+1], m2 = mv[i*3+2];

            float mx = fmaxf(fmaxf(fmaxf(s0.x, s0.y), fmaxf(s0.z, s0.w)),
                       fmaxf(fmaxf(fmaxf(s1.x, s1.y), fmaxf(s1.z, s1.w)),
                             fmaxf(fmaxf(s2.x, s2.y), fmaxf(s2.z, s2.w))));
#pragma unroll
            for (int d = 16; d >= 1; d >>= 1)   // 32-lane half reduction
                mx = fmaxf(mx, __shfl_xor(mx, d, 64));

            const float e0  = __expf(s0.x - mx), e1  = __expf(s0.y - mx);
            const float e2  = __expf(s0.z - mx), e3  = __expf(s0.w - mx);
            const float e4  = __expf(s1.x - mx), e5  = __expf(s1.y - mx);
            const float e6  = __expf(s1.z - mx), e7  = __expf(s1.w - mx);
            const float e8  = __expf(s2.x - mx), e9  = __expf(s2.y - mx);
            const float e10 = __expf(s2.z - mx), e11 = __expf(s2.w - mx);

            float l = (((e0 + e1) + (e2 + e3)) + ((e4 + e5) + (e6 + e7))) +
                      ((e8 + e9) + (e10 + e11));
#pragma unroll
            for (int d = 16; d >= 1; d >>= 1)
                l += __shfl_xor(l, d, 64);
            if (l32 == 0) linv[row] = 1.0f / l;   // normalization deferred

            u32x2 w0, w1, w2;
            w0.x = f2bf(e0  * m0.x) | (f2bf(e1  * m0.y) << 16);
            w0.y = f2bf(e2  * m0.z) | (f2bf(e3  * m0.w) << 16);
            w1.x = f2bf(e4  * m1.x) | (f2bf(e5  * m1.y) << 16);
            w1.y = f2bf(e6  * m1.z) | (f2bf(e7  * m1.w) << 16);
            w2.x = f2bf(e8  * m2.x) | (f2bf(e9  * m2.y) << 16);
            w2.y = f2bf(e10 * m2.z) | (f2bf(e11 * m2.w) << 16);

            // 16B k-group g; octet-XOR swizzle by (row&7) (R4-proven)
            const int xsw = row & 7;
            const int gb  = l32 >> 1;
            unsigned int* prow =
                P32 + row * (PROW / 2) + ((gb ^ xsw) << 2) + ((l32 & 1) << 1);
            *reinterpret_cast<u32x2*>(prow)       = w0;
            *reinterpret_cast<u32x2*>(prow + 64)  = w1;
            *reinterpret_cast<u32x2*>(prow + 128) = w2;
        }

        // sv/mv now dead: issue next tile's 48 KB so it flies through the
        // barrier + MFMA phase (same depth as old double-buffer).
        if (t + 1 < TPB) prefetch(t + 1);

        __syncthreads();   // P + linv visible to all waves

        // ---- phase 1: 12 MFMA steps, A from LDS, B from registers ---------
        f32x4 acc = {};
#pragma unroll
        for (int s = 0; s < 12; ++s) {
            const int kg = s * 4 + quad;   // global k-group 0..47
            const bf16x8 a = *reinterpret_cast<const bf16x8*>(
                &P_lds[qrow * PROW + ((kg ^ qx) << 3)]);
            acc = __builtin_amdgcn_mfma_f32_16x16x32_bf16(a, vfrag[s], acc, 0, 0, 0);
        }

        // ---- epilogue: scale by 1/l, nt-store fp32 ------------------------
        // C/D layout (m89-verified): col = lane&15, row = quad*4 + reg
        const size_t ob   = ((size_t)bh * S + q0) * D;
        const int    orow = quad << 2;
        float iv[4];
#pragma unroll
        for (int r = 0; r < 4; ++r) iv[r] = linv[orow + r];
#pragma unroll
        for (int r = 0; r < 4; ++r) {
            __builtin_nontemporal_store(
                acc[r] * iv[r], out + ob + (size_t)(orow + r) * D + dcol);
        }

        __syncthreads();   // protect P_lds/linv reuse by next tile
    }
}

} // namespace

extern "C" void kernel_launch(void* const* d_in, const int* in_sizes, int n_in,
                              void* d_out, int out_size, void* d_ws, size_t ws_size,
                              hipStream_t stream)
{
    const float* scores = (const float*)d_in[0];  // x429 [B,H,S,S]
    const float* vmat   = (const float*)d_in[1];  // x419 [B,H,S,D]
    const float* dmask  = (const float*)d_in[2];  // dropout_mask [B,H,S,S]
    float* out = (float*)d_out;                   // [B,H,S,D] fp32

    const int BH = 32 * 12;                       // 384
    dim3 grid(BH * 6);                            // 2304 blocks = 9/CU, 3 gens @ 3 resident
    dim3 block(256);
    softmax_drop_pv<<<grid, block, 0, stream>>>(scores, vmat, dmask, out);
}